// Round 5
// baseline (799.796 us; speedup 1.0000x reference)
//
#include <hip/hip_runtime.h>

// TurboQuant MSE: y = FWHT(x*sigma)/32; idx = searchsorted(boundaries, y, left);
// x_hat = sigma * FWHT(centroids[idx]) / 32.
// Outputs: [x_hat (N*D f32), indices (N*D, stored as exact float values)].
//
// One wave per row (D=1024, 16 elems/lane). Butterfly stage order matches the
// reference exactly (h ascending, low slot = a+b, high slot = a-b); every op
// is exact or single-rounded identically, so y (and indices) are bit-exact.
//
// Cross-lane stages: m=1,2,4,8 via ds_swizzle + sign-FMA (1 DS + 1 VALU each);
// m=16,32 via permlane{16,32}_swap pair-butterflies (pure VALU pipe).
//
// NOTE 1: __launch_bounds__ min-waves must stay at 4. Requesting 8 waves/SIMD
// caps the allocator at 64 VGPRs -> v[16] spills to scratch -> ~870 MB extra
// HBM traffic and 3.5x slowdown (measured R3: VGPR=28, WRITE_SIZE 1.38 GB).
//
// NOTE 2: permlane swaps MUST use the __builtin_amdgcn_permlane*_swap
// intrinsics, not inline asm. Inline-asm permlane after a VALU write skips the
// compiler's cross-lane hazard nops; it read stale values in tight codegen
// (R4: absmax 6.5 at launch_bounds(256,4) while the padded spill codegen of
// R3 passed exactly).

constexpr int D_DIM  = 1024;
constexpr int N_ROWS = 65536;
constexpr int ELEMS  = 16;
constexpr int WPB    = 4;   // waves per block

typedef float    f32x4 __attribute__((ext_vector_type(4)));
typedef unsigned u32x2 __attribute__((ext_vector_type(2)));

__device__ __forceinline__ float sgpr_f(float x) {
    return __int_as_float(__builtin_amdgcn_readfirstlane(__float_as_int(x)));
}

// Butterfly via LDS swizzle (xor mask M within 32-lane halves), combine as
// v = fmaf(v, sgn, partner): lower lanes v+p, upper lanes p-v. Exact.
template<int M>
__device__ __forceinline__ void bfly_swz(float v[ELEMS], float sgn) {
#pragma unroll
    for (int j = 0; j < ELEMS; ++j) {
        float p = __int_as_float(
            __builtin_amdgcn_ds_swizzle(__float_as_int(v[j]), (M << 10) | 0x1F));
        v[j] = fmaf(v[j], sgn, p);
    }
}

// swap(a,b) via permlane16_swap: odd 16-lane rows of a <-> even rows of b:
// a' = {a0,b0,a2,b2}, b' = {a1,b1,a3,b3}.
__device__ __forceinline__ void pl16_swap(float& a, float& b) {
    u32x2 r = __builtin_amdgcn_permlane16_swap(
        __float_as_uint(a), __float_as_uint(b), false, false);
    a = __uint_as_float(r[0]);
    b = __uint_as_float(r[1]);
}

__device__ __forceinline__ void pl32_swap(float& a, float& b) {
    u32x2 r = __builtin_amdgcn_permlane32_swap(
        __float_as_uint(a), __float_as_uint(b), false, false);
    a = __uint_as_float(r[0]);
    b = __uint_as_float(r[1]);
}

// m=16 butterfly on a PAIR of elements (pure VALU):
// swap -> s=a+b, d=a-b -> swap back distributes sums to low rows, diffs to high.
__device__ __forceinline__ void bfly_pl16(float& a, float& b) {
    pl16_swap(a, b);
    float s = a + b;
    float d = a - b;
    pl16_swap(s, d);
    a = s;
    b = d;
}

// m=32 butterfly on a pair (swaps 32-lane halves).
__device__ __forceinline__ void bfly_pl32(float& a, float& b) {
    pl32_swap(a, b);
    float s = a + b;
    float d = a - b;
    pl32_swap(s, d);
    a = s;
    b = d;
}

__device__ __forceinline__ void fwht_1024(float v[ELEMS],
                                          float s1, float s2, float s4, float s8) {
    // Intra-lane stages h = 1,2,4,8 (lane holds 16 contiguous elements)
#pragma unroll
    for (int h = 1; h <= 8; h <<= 1) {
#pragma unroll
        for (int i = 0; i < ELEMS; i += 2 * h) {
#pragma unroll
            for (int j = 0; j < h; ++j) {
                float a = v[i + j];
                float b = v[i + j + h];
                v[i + j]     = a + b;
                v[i + j + h] = a - b;
            }
        }
    }
    // Cross-lane stages h = 16..512 (lane-xor masks 1..32, ascending)
    bfly_swz<1>(v, s1);
    bfly_swz<2>(v, s2);
    bfly_swz<4>(v, s4);
    bfly_swz<8>(v, s8);
#pragma unroll
    for (int j = 0; j < ELEMS; j += 2) bfly_pl16(v[j], v[j + 1]);
#pragma unroll
    for (int j = 0; j < ELEMS; j += 2) bfly_pl32(v[j], v[j + 1]);
}

__global__ __launch_bounds__(256, 4) void tq_kernel(
    const float* __restrict__ x,
    const float* __restrict__ sigma,
    const float* __restrict__ centroids,
    const float* __restrict__ boundaries,
    float* __restrict__ out)
{
    __shared__ float c_lds[16];
    if (threadIdx.x < 16) c_lds[threadIdx.x] = centroids[threadIdx.x];
    __syncthreads();

    const int lane = threadIdx.x & 63;
    const size_t row = (size_t)blockIdx.x * WPB + (threadIdx.x >> 6);

    // Boundaries pinned to SGPRs (uniform)
    float bnd[15];
#pragma unroll
    for (int t = 0; t < 15; ++t) bnd[t] = sgpr_f(boundaries[t]);

    const float s1 = (lane & 1) ? -1.0f : 1.0f;
    const float s2 = (lane & 2) ? -1.0f : 1.0f;
    const float s4 = (lane & 4) ? -1.0f : 1.0f;
    const float s8 = (lane & 8) ? -1.0f : 1.0f;

    const f32x4* xr = reinterpret_cast<const f32x4*>(x + row * D_DIM + (size_t)lane * ELEMS);
    const f32x4* sr = reinterpret_cast<const f32x4*>(sigma + (size_t)lane * ELEMS);

    float v[ELEMS];
    unsigned smask = 0;   // bit j = sign bit of sigma[lane*16+j]
#pragma unroll
    for (int q = 0; q < 4; ++q) {
        f32x4 xv = __builtin_nontemporal_load(xr + q);
        f32x4 sv = sr[q];
#pragma unroll
        for (int k = 0; k < 4; ++k) {
            smask |= (__float_as_uint(sv[k]) >> 31) << (4 * q + k);
            v[4 * q + k] = xv[k] * sv[k];   // exact (sigma = +/-1)
        }
    }

    fwht_1024(v, s1, s2, s4, s8);

    // Quantize + store indices immediately (frees registers before 2nd FWHT).
    float* io = out + (size_t)N_ROWS * D_DIM + row * D_DIM + (size_t)lane * ELEMS;
#pragma unroll
    for (int q = 0; q < 4; ++q) {
        f32x4 b;
        float yh[4];
#pragma unroll
        for (int k = 0; k < 4; ++k) {
            const int j = 4 * q + k;
            float y = v[j] * 0.03125f;   // exact 2^-5
            int idx = 0;
#pragma unroll
            for (int t = 0; t < 15; ++t) idx += (bnd[t] < y) ? 1 : 0;
            b[k] = (float)idx;
            yh[k] = c_lds[idx];
        }
#pragma unroll
        for (int k = 0; k < 4; ++k) v[4 * q + k] = yh[k];
        __builtin_nontemporal_store(b, reinterpret_cast<f32x4*>(io) + q);
    }

    fwht_1024(v, s1, s2, s4, s8);

    // x_hat = sigma * (v/32): scale exactly, then flip sign bit per smask (exact).
    float* xo = out + row * D_DIM + (size_t)lane * ELEMS;
#pragma unroll
    for (int q = 0; q < 4; ++q) {
        f32x4 a;
#pragma unroll
        for (int k = 0; k < 4; ++k) {
            const int j = 4 * q + k;
            unsigned sx = (smask >> j) << 31;
            a[k] = __uint_as_float(__float_as_uint(v[j] * 0.03125f) ^ sx);
        }
        __builtin_nontemporal_store(a, reinterpret_cast<f32x4*>(xo) + q);
    }
}

extern "C" void kernel_launch(void* const* d_in, const int* in_sizes, int n_in,
                              void* d_out, int out_size, void* d_ws, size_t ws_size,
                              hipStream_t stream) {
    const float* x          = (const float*)d_in[0];
    const float* sigma      = (const float*)d_in[1];
    const float* centroids  = (const float*)d_in[2];
    const float* boundaries = (const float*)d_in[3];
    float* out = (float*)d_out;

    dim3 grid(N_ROWS / WPB);
    dim3 block(256);
    hipLaunchKernelGGL(tq_kernel, grid, block, 0, stream,
                       x, sigma, centroids, boundaries, out);
}

// Round 6
// 789.577 us; speedup vs baseline: 1.0129x; 1.0129x over previous
//
#include <hip/hip_runtime.h>

// TurboQuant MSE: y = FWHT(x*sigma)/32; idx = searchsorted(boundaries, y, left);
// x_hat = sigma * FWHT(centroids[idx]) / 32.
// Outputs: [x_hat (N*D f32), indices (N*D, stored as exact float values)].
//
// One wave per row (D=1024, 16 elems/lane). Butterfly stage order matches the
// reference exactly (h ascending, low slot = a+b, high slot = a-b); every op
// is exact or single-rounded identically, so y (and indices) are bit-exact.
//
// LESSONS ENCODED HERE:
//  - R2-R5: keeping the 16 per-lane elements in a C array defeated SROA ->
//    alloca in scratch (VGPR_Count=28, +870 MB HBM writes, 800 us, regardless
//    of __launch_bounds__). Fix: 16 NAMED SCALARS, macro-unrolled butterflies.
//    Never reintroduce private arrays here.
//  - R4: permlane swaps MUST use __builtin_amdgcn_permlane*_swap intrinsics,
//    not inline asm (asm skips the compiler's cross-lane hazard nops -> stale
//    reads in tight codegen).

constexpr int D_DIM  = 1024;
constexpr int N_ROWS = 65536;
constexpr int WPB    = 4;   // waves per block

typedef float    f32x4 __attribute__((ext_vector_type(4)));
typedef unsigned u32x2 __attribute__((ext_vector_type(2)));

// ds_swizzle XOR-mask butterfly partner (within 32-lane halves), BitMode:
// offset = (xor<<10) | (or<<5) | and, and=0x1F.
template<int M>
__device__ __forceinline__ float swz(float x) {
    return __int_as_float(
        __builtin_amdgcn_ds_swizzle(__float_as_int(x), (M << 10) | 0x1F));
}

// m=16 butterfly on a PAIR of elements via permlane16_swap (pure VALU):
// swap(a,b) exchanges odd 16-lane rows of a with even rows of b; then
// s=a+b, d=a-b; swapping back distributes sums to low rows, diffs to high.
// Bit-exact vs reference (verified R3/R5, absmax 0.0).
__device__ __forceinline__ void bfly_pl16(float& a, float& b) {
    u32x2 r = __builtin_amdgcn_permlane16_swap(
        __float_as_uint(a), __float_as_uint(b), false, false);
    float ra = __uint_as_float(r[0]);
    float rb = __uint_as_float(r[1]);
    float s = ra + rb;
    float d = ra - rb;
    u32x2 r2 = __builtin_amdgcn_permlane16_swap(
        __float_as_uint(s), __float_as_uint(d), false, false);
    a = __uint_as_float(r2[0]);
    b = __uint_as_float(r2[1]);
}

// m=32 butterfly on a pair via permlane32_swap (swaps 32-lane halves).
__device__ __forceinline__ void bfly_pl32(float& a, float& b) {
    u32x2 r = __builtin_amdgcn_permlane32_swap(
        __float_as_uint(a), __float_as_uint(b), false, false);
    float ra = __uint_as_float(r[0]);
    float rb = __uint_as_float(r[1]);
    float s = ra + rb;
    float d = ra - rb;
    u32x2 r2 = __builtin_amdgcn_permlane32_swap(
        __float_as_uint(s), __float_as_uint(d), false, false);
    a = __uint_as_float(r2[0]);
    b = __uint_as_float(r2[1]);
}

#define BFLY(a, b) { float _s = (a) + (b); float _d = (a) - (b); (a) = _s; (b) = _d; }

// Intra-lane FWHT stages h = 1,2,4,8 over 16 named scalars.
#define INTRA_ALL() \
  BFLY(v0,v1)  BFLY(v2,v3)  BFLY(v4,v5)  BFLY(v6,v7)   \
  BFLY(v8,v9)  BFLY(v10,v11) BFLY(v12,v13) BFLY(v14,v15) \
  BFLY(v0,v2)  BFLY(v1,v3)  BFLY(v4,v6)  BFLY(v5,v7)   \
  BFLY(v8,v10) BFLY(v9,v11) BFLY(v12,v14) BFLY(v13,v15) \
  BFLY(v0,v4)  BFLY(v1,v5)  BFLY(v2,v6)  BFLY(v3,v7)   \
  BFLY(v8,v12) BFLY(v9,v13) BFLY(v10,v14) BFLY(v11,v15) \
  BFLY(v0,v8)  BFLY(v1,v9)  BFLY(v2,v10) BFLY(v3,v11)  \
  BFLY(v4,v12) BFLY(v5,v13) BFLY(v6,v14) BFLY(v7,v15)

// Cross-lane stage via ds_swizzle + sign-FMA: low lanes v+p, high lanes p-v.
#define SWZ_ALL(M, sg) \
  v0  = fmaf(v0,  sg, swz<M>(v0));  v1  = fmaf(v1,  sg, swz<M>(v1));  \
  v2  = fmaf(v2,  sg, swz<M>(v2));  v3  = fmaf(v3,  sg, swz<M>(v3));  \
  v4  = fmaf(v4,  sg, swz<M>(v4));  v5  = fmaf(v5,  sg, swz<M>(v5));  \
  v6  = fmaf(v6,  sg, swz<M>(v6));  v7  = fmaf(v7,  sg, swz<M>(v7));  \
  v8  = fmaf(v8,  sg, swz<M>(v8));  v9  = fmaf(v9,  sg, swz<M>(v9));  \
  v10 = fmaf(v10, sg, swz<M>(v10)); v11 = fmaf(v11, sg, swz<M>(v11)); \
  v12 = fmaf(v12, sg, swz<M>(v12)); v13 = fmaf(v13, sg, swz<M>(v13)); \
  v14 = fmaf(v14, sg, swz<M>(v14)); v15 = fmaf(v15, sg, swz<M>(v15));

#define PL16_ALL() \
  bfly_pl16(v0,v1);   bfly_pl16(v2,v3);   bfly_pl16(v4,v5);   bfly_pl16(v6,v7); \
  bfly_pl16(v8,v9);   bfly_pl16(v10,v11); bfly_pl16(v12,v13); bfly_pl16(v14,v15);

#define PL32_ALL() \
  bfly_pl32(v0,v1);   bfly_pl32(v2,v3);   bfly_pl32(v4,v5);   bfly_pl32(v6,v7); \
  bfly_pl32(v8,v9);   bfly_pl32(v10,v11); bfly_pl32(v12,v13); bfly_pl32(v14,v15);

// Full 1024-pt FWHT (stage order = reference: h = 1..512 ascending).
#define FWHT1024() \
  INTRA_ALL()      \
  SWZ_ALL(1, s1)   \
  SWZ_ALL(2, s2)   \
  SWZ_ALL(4, s4)   \
  SWZ_ALL(8, s8)   \
  PL16_ALL()       \
  PL32_ALL()

__global__ __launch_bounds__(256, 4) void tq_kernel(
    const float* __restrict__ x,
    const float* __restrict__ sigma,
    const float* __restrict__ centroids,
    const float* __restrict__ boundaries,
    float* __restrict__ out)
{
    __shared__ float c_lds[16];
    if (threadIdx.x < 16) c_lds[threadIdx.x] = centroids[threadIdx.x];
    __syncthreads();

    const int lane = threadIdx.x & 63;
    const size_t row = (size_t)blockIdx.x * WPB + (threadIdx.x >> 6);

    // Boundaries as 15 named scalars (uniform -> scalar loads/SGPRs).
    const float bnd0  = boundaries[0],  bnd1  = boundaries[1];
    const float bnd2  = boundaries[2],  bnd3  = boundaries[3];
    const float bnd4  = boundaries[4],  bnd5  = boundaries[5];
    const float bnd6  = boundaries[6],  bnd7  = boundaries[7];
    const float bnd8  = boundaries[8],  bnd9  = boundaries[9];
    const float bnd10 = boundaries[10], bnd11 = boundaries[11];
    const float bnd12 = boundaries[12], bnd13 = boundaries[13];
    const float bnd14 = boundaries[14];

    const float s1 = (lane & 1) ? -1.0f : 1.0f;
    const float s2 = (lane & 2) ? -1.0f : 1.0f;
    const float s4 = (lane & 4) ? -1.0f : 1.0f;
    const float s8 = (lane & 8) ? -1.0f : 1.0f;

    const f32x4* xr4 = reinterpret_cast<const f32x4*>(x + row * D_DIM + (size_t)lane * 16);
    const f32x4* sr4 = reinterpret_cast<const f32x4*>(sigma + (size_t)lane * 16);

    float v0, v1, v2, v3, v4, v5, v6, v7, v8, v9, v10, v11, v12, v13, v14, v15;
    unsigned smask = 0;   // bit j = sign bit of sigma[lane*16+j]

#define LOADQ(Q, A, B, C, Dv) {                                   \
    f32x4 xv = __builtin_nontemporal_load(xr4 + Q);               \
    f32x4 sv = sr4[Q];                                            \
    smask |= (__float_as_uint(sv[0]) >> 31) << (4*Q + 0);         \
    smask |= (__float_as_uint(sv[1]) >> 31) << (4*Q + 1);         \
    smask |= (__float_as_uint(sv[2]) >> 31) << (4*Q + 2);         \
    smask |= (__float_as_uint(sv[3]) >> 31) << (4*Q + 3);         \
    A = xv[0] * sv[0];  B = xv[1] * sv[1];                        \
    C = xv[2] * sv[2];  Dv = xv[3] * sv[3]; }

    LOADQ(0, v0,  v1,  v2,  v3)
    LOADQ(1, v4,  v5,  v6,  v7)
    LOADQ(2, v8,  v9,  v10, v11)
    LOADQ(3, v12, v13, v14, v15)
#undef LOADQ

    FWHT1024()

    // Quantize; store indices immediately (frees live range before 2nd FWHT).
    f32x4* io4 = reinterpret_cast<f32x4*>(
        out + (size_t)N_ROWS * D_DIM + row * D_DIM + (size_t)lane * 16);

#define QUANT1(a, slot) {                                                     \
    float y = (a) * 0.03125f;  /* exact 2^-5 */                               \
    int idx = (bnd0  < y) + (bnd1  < y) + (bnd2  < y) + (bnd3  < y)           \
            + (bnd4  < y) + (bnd5  < y) + (bnd6  < y) + (bnd7  < y)           \
            + (bnd8  < y) + (bnd9  < y) + (bnd10 < y) + (bnd11 < y)           \
            + (bnd12 < y) + (bnd13 < y) + (bnd14 < y);                        \
    slot = (float)idx;                                                        \
    (a) = c_lds[idx]; }

#define QUANTQ(Q, A, B, C, Dv) {      \
    f32x4 bb;                         \
    QUANT1(A, bb[0])                  \
    QUANT1(B, bb[1])                  \
    QUANT1(C, bb[2])                  \
    QUANT1(Dv, bb[3])                 \
    __builtin_nontemporal_store(bb, io4 + Q); }

    QUANTQ(0, v0,  v1,  v2,  v3)
    QUANTQ(1, v4,  v5,  v6,  v7)
    QUANTQ(2, v8,  v9,  v10, v11)
    QUANTQ(3, v12, v13, v14, v15)
#undef QUANTQ
#undef QUANT1

    FWHT1024()

    // x_hat = sigma * (v/32): exact scale, then exact sign-bit flip per smask.
    f32x4* xo4 = reinterpret_cast<f32x4*>(out + row * D_DIM + (size_t)lane * 16);

#define STORE1(a, J, slot) \
    slot = __uint_as_float(__float_as_uint((a) * 0.03125f) ^ (((smask >> (J)) & 1u) << 31));

#define STOREQ(Q, A, B, C, Dv) {      \
    f32x4 aa;                         \
    STORE1(A, 4*Q + 0, aa[0])         \
    STORE1(B, 4*Q + 1, aa[1])         \
    STORE1(C, 4*Q + 2, aa[2])         \
    STORE1(Dv, 4*Q + 3, aa[3])        \
    __builtin_nontemporal_store(aa, xo4 + Q); }

    STOREQ(0, v0,  v1,  v2,  v3)
    STOREQ(1, v4,  v5,  v6,  v7)
    STOREQ(2, v8,  v9,  v10, v11)
    STOREQ(3, v12, v13, v14, v15)
#undef STOREQ
#undef STORE1
}

extern "C" void kernel_launch(void* const* d_in, const int* in_sizes, int n_in,
                              void* d_out, int out_size, void* d_ws, size_t ws_size,
                              hipStream_t stream) {
    const float* x          = (const float*)d_in[0];
    const float* sigma      = (const float*)d_in[1];
    const float* centroids  = (const float*)d_in[2];
    const float* boundaries = (const float*)d_in[3];
    float* out = (float*)d_out;

    dim3 grid(N_ROWS / WPB);
    dim3 block(256);
    hipLaunchKernelGGL(tq_kernel, grid, block, 0, stream,
                       x, sigma, centroids, boundaries, out);
}

// Round 7
// 121.288 us; speedup vs baseline: 6.5942x; 6.5099x over previous
//
#include <hip/hip_runtime.h>

// TurboQuant MSE: y = FWHT(x*sigma)/32; idx = searchsorted(boundaries, y, left);
// x_hat = sigma * FWHT(centroids[idx]) / 32.
// Outputs: [x_hat (N*D f32), indices (N*D, stored as exact float values)].
//
// One wave per row (D=1024). Lane l owns elements { j4*256 + l*4 + k } for
// j4,k in 0..3 (register r = j4*4+k). Every 16B f32x4 global access is thus
// 64 lanes x 16B CONTIGUOUS = 1KB full lines per instruction.
//
// FWHT stage order matches the reference exactly (h = 1..512 ascending,
// low slot = a+b, high slot = a-b); element bit layout: k = bits 0-1 (intra),
// lane = bits 2-7 (ds_swizzle masks 1..16, permlane32 for bit 7), j4 = bits
// 8-9 (intra). All ops exact or single-rounded identically -> y bit-exact.
//
// LESSONS (measured):
//  - R2-R6 800us regression: NT stores with 64B lane stride (16B/lane) bypass
//    L2 write-merge -> partial-line HBM writes, WRITE_SIZE 2.7x (1.39 GB),
//    1.9 TB/s. NT is only safe when each store instruction covers full lines
//    (this file's layout does: 1KB contiguous per instruction).
//  - R4: permlane swaps MUST use __builtin_amdgcn_permlane*_swap intrinsics,
//    not inline asm (asm skips cross-lane hazard nops -> stale reads).

constexpr int D_DIM  = 1024;
constexpr int N_ROWS = 65536;
constexpr int WPB    = 4;   // waves per block

typedef float    f32x4 __attribute__((ext_vector_type(4)));
typedef unsigned u32x2 __attribute__((ext_vector_type(2)));

// ds_swizzle XOR-mask butterfly partner (within 32-lane halves), BitMode:
// offset = (xor<<10) | (or<<5) | and, and=0x1F.
template<int M>
__device__ __forceinline__ float swz(float x) {
    return __int_as_float(
        __builtin_amdgcn_ds_swizzle(__float_as_int(x), (M << 10) | 0x1F));
}

// Lane-xor-32 butterfly on a PAIR of registers via permlane32_swap (pure
// VALU, hazard-safe builtin). After swap: a'={a.lo,b.lo}, b'={a.hi,b.hi};
// s=a'+b', d=a'-d'... s/d hold per-register sums/diffs; swapping back puts
// sums in low halves, diffs in high halves of each register. Bit-exact
// (verified R5/R6, absmax 0.0).
__device__ __forceinline__ void bfly_pl32(float& a, float& b) {
    u32x2 r = __builtin_amdgcn_permlane32_swap(
        __float_as_uint(a), __float_as_uint(b), false, false);
    float ra = __uint_as_float(r[0]);
    float rb = __uint_as_float(r[1]);
    float s = ra + rb;
    float d = ra - rb;
    u32x2 r2 = __builtin_amdgcn_permlane32_swap(
        __float_as_uint(s), __float_as_uint(d), false, false);
    a = __uint_as_float(r2[0]);
    b = __uint_as_float(r2[1]);
}

#define BFLY(a, b) { float _s = (a) + (b); float _d = (a) - (b); (a) = _s; (b) = _d; }

// Cross-lane stage via ds_swizzle + sign-FMA: low lanes v+p, high lanes p-v.
#define SWZ_ALL(M, sg) \
  v0  = fmaf(v0,  sg, swz<M>(v0));  v1  = fmaf(v1,  sg, swz<M>(v1));  \
  v2  = fmaf(v2,  sg, swz<M>(v2));  v3  = fmaf(v3,  sg, swz<M>(v3));  \
  v4  = fmaf(v4,  sg, swz<M>(v4));  v5  = fmaf(v5,  sg, swz<M>(v5));  \
  v6  = fmaf(v6,  sg, swz<M>(v6));  v7  = fmaf(v7,  sg, swz<M>(v7));  \
  v8  = fmaf(v8,  sg, swz<M>(v8));  v9  = fmaf(v9,  sg, swz<M>(v9));  \
  v10 = fmaf(v10, sg, swz<M>(v10)); v11 = fmaf(v11, sg, swz<M>(v11)); \
  v12 = fmaf(v12, sg, swz<M>(v12)); v13 = fmaf(v13, sg, swz<M>(v13)); \
  v14 = fmaf(v14, sg, swz<M>(v14)); v15 = fmaf(v15, sg, swz<M>(v15));

#define PL32_ALL() \
  bfly_pl32(v0,v1);   bfly_pl32(v2,v3);   bfly_pl32(v4,v5);   bfly_pl32(v6,v7); \
  bfly_pl32(v8,v9);   bfly_pl32(v10,v11); bfly_pl32(v12,v13); bfly_pl32(v14,v15);

// Full 1024-pt FWHT, ascending h. Register r = j4*4+k; element = j4*256+l*4+k.
//  h=1   : k bit 0  -> BFLY(r, r+1), even r
//  h=2   : k bit 1  -> BFLY(r, r+2), r in {0,1,4,5,8,9,12,13}
//  h=4..64  : lane bits 0..4 -> ds_swizzle masks 1,2,4,8,16
//  h=128 : lane bit 5 -> permlane32 pair butterfly
//  h=256 : j4 bit 0 -> BFLY(r, r+4), r in {0..3, 8..11}
//  h=512 : j4 bit 1 -> BFLY(r, r+8), r in {0..7}
#define FWHT1024() \
  BFLY(v0,v1)  BFLY(v2,v3)   BFLY(v4,v5)   BFLY(v6,v7)   \
  BFLY(v8,v9)  BFLY(v10,v11) BFLY(v12,v13) BFLY(v14,v15) \
  BFLY(v0,v2)  BFLY(v1,v3)   BFLY(v4,v6)   BFLY(v5,v7)   \
  BFLY(v8,v10) BFLY(v9,v11)  BFLY(v12,v14) BFLY(v13,v15) \
  SWZ_ALL(1,  sg1)  \
  SWZ_ALL(2,  sg2)  \
  SWZ_ALL(4,  sg4)  \
  SWZ_ALL(8,  sg8)  \
  SWZ_ALL(16, sg16) \
  PL32_ALL()        \
  BFLY(v0,v4)  BFLY(v1,v5)   BFLY(v2,v6)   BFLY(v3,v7)   \
  BFLY(v8,v12) BFLY(v9,v13)  BFLY(v10,v14) BFLY(v11,v15) \
  BFLY(v0,v8)  BFLY(v1,v9)   BFLY(v2,v10)  BFLY(v3,v11)  \
  BFLY(v4,v12) BFLY(v5,v13)  BFLY(v6,v14)  BFLY(v7,v15)

__global__ __launch_bounds__(256, 4) void tq_kernel(
    const float* __restrict__ x,
    const float* __restrict__ sigma,
    const float* __restrict__ centroids,
    const float* __restrict__ boundaries,
    float* __restrict__ out)
{
    __shared__ float c_lds[16];
    if (threadIdx.x < 16) c_lds[threadIdx.x] = centroids[threadIdx.x];
    __syncthreads();

    const int lane = threadIdx.x & 63;
    const size_t row = (size_t)blockIdx.x * WPB + (threadIdx.x >> 6);

    // Boundaries as 15 named scalars (uniform -> scalar loads).
    const float bnd0  = boundaries[0],  bnd1  = boundaries[1];
    const float bnd2  = boundaries[2],  bnd3  = boundaries[3];
    const float bnd4  = boundaries[4],  bnd5  = boundaries[5];
    const float bnd6  = boundaries[6],  bnd7  = boundaries[7];
    const float bnd8  = boundaries[8],  bnd9  = boundaries[9];
    const float bnd10 = boundaries[10], bnd11 = boundaries[11];
    const float bnd12 = boundaries[12], bnd13 = boundaries[13];
    const float bnd14 = boundaries[14];

    // Signs for cross-lane stages (lane bit set -> this lane gets p - v).
    const float sg1  = (lane & 1)  ? -1.0f : 1.0f;
    const float sg2  = (lane & 2)  ? -1.0f : 1.0f;
    const float sg4  = (lane & 4)  ? -1.0f : 1.0f;
    const float sg8  = (lane & 8)  ? -1.0f : 1.0f;
    const float sg16 = (lane & 16) ? -1.0f : 1.0f;

    // Element base for register group j4: row*1024 + j4*256 + lane*4.
    const size_t base = row * D_DIM + (size_t)lane * 4;

    float v0, v1, v2, v3, v4, v5, v6, v7, v8, v9, v10, v11, v12, v13, v14, v15;
    unsigned smask = 0;   // bit r = sign bit of sigma[element(r)]

#define LOADQ(J4, A, B, C, Dv) {                                        \
    f32x4 xv = *reinterpret_cast<const f32x4*>(x + base + (J4) * 256);  \
    f32x4 sv = *reinterpret_cast<const f32x4*>(sigma + (size_t)lane * 4 + (J4) * 256); \
    smask |= (__float_as_uint(sv[0]) >> 31) << (4*(J4) + 0);            \
    smask |= (__float_as_uint(sv[1]) >> 31) << (4*(J4) + 1);            \
    smask |= (__float_as_uint(sv[2]) >> 31) << (4*(J4) + 2);            \
    smask |= (__float_as_uint(sv[3]) >> 31) << (4*(J4) + 3);            \
    A = xv[0] * sv[0];  B = xv[1] * sv[1];                              \
    C = xv[2] * sv[2];  Dv = xv[3] * sv[3]; }

    LOADQ(0, v0,  v1,  v2,  v3)
    LOADQ(1, v4,  v5,  v6,  v7)
    LOADQ(2, v8,  v9,  v10, v11)
    LOADQ(3, v12, v13, v14, v15)
#undef LOADQ

    FWHT1024()

    // Quantize; store indices immediately (shortens live ranges).
    float* iobase = out + (size_t)N_ROWS * D_DIM + base;

#define QUANT1(a, slot) {                                                     \
    float y = (a) * 0.03125f;  /* exact 2^-5 */                               \
    int idx = (bnd0  < y) + (bnd1  < y) + (bnd2  < y) + (bnd3  < y)           \
            + (bnd4  < y) + (bnd5  < y) + (bnd6  < y) + (bnd7  < y)           \
            + (bnd8  < y) + (bnd9  < y) + (bnd10 < y) + (bnd11 < y)           \
            + (bnd12 < y) + (bnd13 < y) + (bnd14 < y);                        \
    slot = (float)idx;                                                        \
    (a) = c_lds[idx]; }

#define QUANTQ(J4, A, B, C, Dv) {     \
    f32x4 bb;                         \
    QUANT1(A, bb[0])                  \
    QUANT1(B, bb[1])                  \
    QUANT1(C, bb[2])                  \
    QUANT1(Dv, bb[3])                 \
    __builtin_nontemporal_store(bb, reinterpret_cast<f32x4*>(iobase + (J4) * 256)); }

    QUANTQ(0, v0,  v1,  v2,  v3)
    QUANTQ(1, v4,  v5,  v6,  v7)
    QUANTQ(2, v8,  v9,  v10, v11)
    QUANTQ(3, v12, v13, v14, v15)
#undef QUANTQ
#undef QUANT1

    FWHT1024()

    // x_hat = sigma * (v/32): exact scale, then exact sign-bit flip per smask.
    float* xobase = out + base;

#define STORE1(a, R, slot) \
    slot = __uint_as_float(__float_as_uint((a) * 0.03125f) ^ (((smask >> (R)) & 1u) << 31));

#define STOREQ(J4, A, B, C, Dv) {     \
    f32x4 aa;                         \
    STORE1(A, 4*(J4) + 0, aa[0])      \
    STORE1(B, 4*(J4) + 1, aa[1])      \
    STORE1(C, 4*(J4) + 2, aa[2])      \
    STORE1(Dv, 4*(J4) + 3, aa[3])     \
    __builtin_nontemporal_store(aa, reinterpret_cast<f32x4*>(xobase + (J4) * 256)); }

    STOREQ(0, v0,  v1,  v2,  v3)
    STOREQ(1, v4,  v5,  v6,  v7)
    STOREQ(2, v8,  v9,  v10, v11)
    STOREQ(3, v12, v13, v14, v15)
#undef STOREQ
#undef STORE1
}

extern "C" void kernel_launch(void* const* d_in, const int* in_sizes, int n_in,
                              void* d_out, int out_size, void* d_ws, size_t ws_size,
                              hipStream_t stream) {
    const float* x          = (const float*)d_in[0];
    const float* sigma      = (const float*)d_in[1];
    const float* centroids  = (const float*)d_in[2];
    const float* boundaries = (const float*)d_in[3];
    float* out = (float*)d_out;

    dim3 grid(N_ROWS / WPB);
    dim3 block(256);
    hipLaunchKernelGGL(tq_kernel, grid, block, 0, stream,
                       x, sigma, centroids, boundaries, out);
}